// Round 2
// baseline (649.702 us; speedup 1.0000x reference)
//
#include <hip/hip_runtime.h>
#include <cstdint>
#include <cstddef>

// DinoDecoderBlock on MI355X (gfx950).
// B=4 NQ=NK=1024 C=768 H=12 DH=64, scale=1/8, eps=1e-5.
// Strategy: bf16 MFMA for all GEMMs + two-pass in-LDS attention. fp32 residual stream.

typedef __bf16 bf16;
typedef __attribute__((ext_vector_type(8))) __bf16 bf16x8;
typedef __attribute__((ext_vector_type(4))) float f32x4;

typedef __attribute__((address_space(1))) void gvoid;
typedef __attribute__((address_space(3))) void lvoid;

#define DEVI static __device__ __forceinline__

DEVI void gload16(const void* g, void* l) {
  __builtin_amdgcn_global_load_lds((gvoid*)(uintptr_t)g, (lvoid*)(uintptr_t)l, 16, 0, 0);
}

DEVI f32x4 mfma_bf16(bf16x8 a, bf16x8 b, f32x4 c) {
  return __builtin_amdgcn_mfma_f32_16x16x32_bf16(a, b, c, 0, 0, 0);
}

// ---------------- mask dtype detection ----------------
// jax bool mask may arrive as 1-byte bools (shift=0) or int32 0/1 words (shift=2).
// For int32 little-endian 0/1 data, bytes at idx%4 != 0 are all zero.
__global__ __launch_bounds__(256)
void detect_mask_k(const unsigned char* __restrict__ mask, int* __restrict__ shift)
{
  __shared__ int acc[256];
  const int t = threadIdx.x;
  int s = 0;
  for (int i = t; i < 16384; i += 256) {
    const int base = i * 4;
    s += mask[base + 1] + mask[base + 2] + mask[base + 3];
  }
  acc[t] = s;
  __syncthreads();
  #pragma unroll
  for (int o = 128; o; o >>= 1) {
    if (t < o) acc[t] += acc[t + o];
    __syncthreads();
  }
  if (t == 0) *shift = (acc[0] == 0) ? 2 : 0;
}

// ---------------- fp32 -> bf16 convert ----------------
__global__ __launch_bounds__(256)
void cvt_k(const float* __restrict__ s, bf16* __restrict__ d, int n4)
{
  const int i = blockIdx.x * 256 + threadIdx.x;
  if (i >= n4) return;
  const f32x4 v = *((const f32x4*)s + i);
  bf16* o = d + (size_t)i * 4;
  o[0] = (bf16)v[0]; o[1] = (bf16)v[1]; o[2] = (bf16)v[2]; o[3] = (bf16)v[3];
}

// ---------------- float4 copy ----------------
__global__ __launch_bounds__(256)
void copy4_k(const float* __restrict__ s, float* __restrict__ d, int n4)
{
  const int i = blockIdx.x * 256 + threadIdx.x;
  if (i < n4) ((f32x4*)d)[i] = ((const f32x4*)s)[i];
}

// ---------------- LayerNorm over 768, fp32 in -> bf16 out ----------------
__global__ __launch_bounds__(256)
void ln_k(const float* __restrict__ xin, const float* __restrict__ g,
          const float* __restrict__ be, bf16* __restrict__ out)
{
  const int row = blockIdx.x, tid = threadIdx.x;
  const int lane = tid & 63, w = tid >> 6;
  const float* xr = xin + (size_t)row * 768;
  const float v0 = xr[tid], v1 = xr[tid + 256], v2 = xr[tid + 512];
  float s = v0 + v1 + v2;
  #pragma unroll
  for (int o = 32; o; o >>= 1) s += __shfl_xor(s, o);
  __shared__ float r1[4], r2[4];
  if (lane == 0) r1[w] = s;
  __syncthreads();
  const float mean = (r1[0] + r1[1] + r1[2] + r1[3]) * (1.0f / 768.0f);
  const float d0 = v0 - mean, d1 = v1 - mean, d2 = v2 - mean;
  float q = d0 * d0 + d1 * d1 + d2 * d2;
  #pragma unroll
  for (int o = 32; o; o >>= 1) q += __shfl_xor(q, o);
  if (lane == 0) r2[w] = q;
  __syncthreads();
  const float inv = rsqrtf((r2[0] + r2[1] + r2[2] + r2[3]) * (1.0f / 768.0f) + 1e-5f);
  bf16* orow = out + (size_t)row * 768;
  orow[tid]       = (bf16)(d0 * inv * g[tid]       + be[tid]);
  orow[tid + 256] = (bf16)(d1 * inv * g[tid + 256] + be[tid + 256]);
  orow[tid + 512] = (bf16)(d2 * inv * g[tid + 512] + be[tid + 512]);
}

// ---------------- mean over heads of similarities ----------------
__global__ __launch_bounds__(256)
void simmean_k(const float* __restrict__ sim, float* __restrict__ sm)
{
  const int i = blockIdx.x * 256 + threadIdx.x;   // f32x4 index, total 1048576
  const int b = i >> 18;                           // / (1024*1024/4)
  const int r = i & 262143;
  const f32x4* base = (const f32x4*)sim + (size_t)b * 12 * 262144 + r;
  f32x4 a = base[0];
  #pragma unroll
  for (int h = 1; h < 12; ++h) a += base[(size_t)h * 262144];
  ((f32x4*)sm)[i] = a * (1.0f / 12.0f);
}

// ---------------- V transpose: src[(b*1024+n)*ld + h*64 + d] -> vt[(bh*64+d)*1024 + n] ----------------
__global__ __launch_bounds__(256)
void build_vt(const bf16* __restrict__ src, int ld, bf16* __restrict__ vt)
{
  __shared__ unsigned short t[64][72];
  const int bh = blockIdx.x, nt = blockIdx.y;
  const int b = bh / 12, hh = bh % 12;
  const int tid = threadIdx.x;
  {
    const int nl = tid >> 2, d0 = (tid & 3) * 16;
    const unsigned short* srow = (const unsigned short*)src
        + (size_t)(b * 1024 + nt * 64 + nl) * ld + hh * 64 + d0;
    #pragma unroll
    for (int j = 0; j < 4; ++j)
      *(ushort4*)(&t[nl][d0 + j * 4]) = *(const ushort4*)(srow + j * 4);
  }
  __syncthreads();
  {
    const int dl = tid >> 2, n0 = (tid & 3) * 16;
    unsigned short* drow = (unsigned short*)vt + ((size_t)bh * 64 + dl) * 1024 + nt * 64 + n0;
    #pragma unroll
    for (int j = 0; j < 4; ++j) {
      ushort4 o;
      o.x = t[n0 + j * 4 + 0][dl];
      o.y = t[n0 + j * 4 + 1][dl];
      o.z = t[n0 + j * 4 + 2][dl];
      o.w = t[n0 + j * 4 + 3][dl];
      *(ushort4*)(drow + j * 4) = o;
    }
  }
}

// ---------------- GEMM: C[M,N] = A[M,K] * Bt[N,K]^T  (bf16 in, fp32 acc) ----------------
// 128x128 tile, BK=64, 4 waves (2x2), global_load_lds staging (m97 structure).
template<bool BIAS, bool GELU, bool RES, bool OBF>
__global__ __launch_bounds__(256)
void gemm_bt(const bf16* __restrict__ A, const bf16* __restrict__ Bt,
             const float* __restrict__ bias, const float* __restrict__ res,
             bf16* __restrict__ Cb, float* __restrict__ Cf,
             int M, int N, int K)
{
  __shared__ bf16 As[128 * 64];
  __shared__ bf16 Bs[128 * 64];
  const int tid = threadIdx.x;
  const int lane = tid & 63;
  const int wv = tid >> 6;
  const int wr = wv >> 1, wc = wv & 1;
  const int l15 = lane & 15, lg = lane >> 4;
  const int bm = blockIdx.y * 128, bn = blockIdx.x * 128;
  (void)M;

  f32x4 acc[4][4];
  const f32x4 z = {0.f, 0.f, 0.f, 0.f};
  #pragma unroll
  for (int i = 0; i < 4; ++i)
    #pragma unroll
    for (int j = 0; j < 4; ++j) acc[i][j] = z;

  for (int k0 = 0; k0 < K; k0 += 64) {
    __syncthreads();               // prior iter's ds_reads done before overwrite
    #pragma unroll
    for (int i = 0; i < 4; ++i) {
      const int c = wv * 256 + i * 64 + lane;   // 16B chunk id, 0..1023
      const int row = c >> 3;                   // tile row (128 rows x 128B)
      const int colb = (c & 7) << 4;            // byte col within 128B row
      gload16((const char*)A  + ((size_t)(bm + row) * K + k0) * 2 + colb,
              (char*)As + (size_t)c * 16);
      gload16((const char*)Bt + ((size_t)(bn + row) * K + k0) * 2 + colb,
              (char*)Bs + (size_t)c * 16);
    }
    __syncthreads();               // barrier drains vmcnt -> LDS ready
    #pragma unroll
    for (int kk = 0; kk < 64; kk += 32) {
      bf16x8 af[4], bfr[4];
      #pragma unroll
      for (int mi = 0; mi < 4; ++mi)
        af[mi] = *(const bf16x8*)(As + (size_t)(wr * 64 + mi * 16 + l15) * 64 + kk + lg * 8);
      #pragma unroll
      for (int ni = 0; ni < 4; ++ni)
        bfr[ni] = *(const bf16x8*)(Bs + (size_t)(wc * 64 + ni * 16 + l15) * 64 + kk + lg * 8);
      #pragma unroll
      for (int mi = 0; mi < 4; ++mi)
        #pragma unroll
        for (int ni = 0; ni < 4; ++ni)
          acc[mi][ni] = mfma_bf16(af[mi], bfr[ni], acc[mi][ni]);
    }
  }

  #pragma unroll
  for (int mi = 0; mi < 4; ++mi) {
    const int row0 = bm + wr * 64 + mi * 16 + lg * 4;
    #pragma unroll
    for (int ni = 0; ni < 4; ++ni) {
      const int col = bn + wc * 64 + ni * 16 + l15;
      #pragma unroll
      for (int r = 0; r < 4; ++r) {
        float v = acc[mi][ni][r];
        if constexpr (BIAS) v += bias[col];
        if constexpr (GELU) v = 0.5f * v * (1.0f + erff(v * 0.70710678118654752f));
        if constexpr (RES)  v += res[(size_t)(row0 + r) * N + col];
        if constexpr (OBF)  Cb[(size_t)(row0 + r) * N + col] = (bf16)v;
        else                Cf[(size_t)(row0 + r) * N + col] = v;
      }
    }
  }
}

// ---------------- attention: one (b, h, 32 q-rows) per block, 8 waves ----------------
// phase1: S = Q K^T (*1/8) [+ sim - simmean, mask] -> LDS fp32 [32][1028]
// phase2: row softmax, write P bf16 in place
// phase3: O = P V  via Vt[bh*64+d][n]
template<int CROSS>
__global__ __launch_bounds__(512)
void attn_k(const bf16* __restrict__ Qp, int ldq,
            const bf16* __restrict__ Kp, int ldk,
            const bf16* __restrict__ Vt,
            const float* __restrict__ sim,
            const float* __restrict__ smean,
            const unsigned char* __restrict__ mask,
            const int* __restrict__ mshift,
            bf16* __restrict__ Out)
{
  __shared__ float S[32][1028];
  __shared__ bf16 Qs[32][72];
  const int hh = blockIdx.x, qt = blockIdx.y, b = blockIdx.z;
  const int tid = threadIdx.x, lane = tid & 63, w = tid >> 6;
  const int l15 = lane & 15, lg = lane >> 4;
  int msh = 0;
  if constexpr (CROSS) msh = *mshift;

  { // stage Q tile [32 x 64]
    const int r = tid >> 4, c4 = (tid & 15) << 2;
    const bf16* srcp = Qp + (size_t)(b * 1024 + qt * 32 + r) * ldq + hh * 64 + c4;
    *(ushort4*)(&Qs[r][c4]) = *(const ushort4*)srcp;
  }
  __syncthreads();

  { // phase 1: wave w owns cols [w*128, w*128+128)
    f32x4 sacc[2][8];
    const f32x4 z = {0.f, 0.f, 0.f, 0.f};
    #pragma unroll
    for (int i = 0; i < 2; ++i)
      #pragma unroll
      for (int j = 0; j < 8; ++j) sacc[i][j] = z;
    const bf16* Kb = Kp + (size_t)b * 1024 * ldk + hh * 64;
    #pragma unroll
    for (int kk = 0; kk < 64; kk += 32) {
      const bf16x8 aq0 = *(const bf16x8*)(&Qs[l15][kk + lg * 8]);
      const bf16x8 aq1 = *(const bf16x8*)(&Qs[16 + l15][kk + lg * 8]);
      #pragma unroll
      for (int ni = 0; ni < 8; ++ni) {
        const bf16x8 bk = *(const bf16x8*)(Kb + (size_t)(w * 128 + ni * 16 + l15) * ldk + kk + lg * 8);
        sacc[0][ni] = mfma_bf16(aq0, bk, sacc[0][ni]);
        sacc[1][ni] = mfma_bf16(aq1, bk, sacc[1][ni]);
      }
    }
    #pragma unroll
    for (int mi = 0; mi < 2; ++mi) {
      const int rq = mi * 16 + lg * 4;
      #pragma unroll
      for (int ni = 0; ni < 8; ++ni) {
        const int col = w * 128 + ni * 16 + l15;
        #pragma unroll
        for (int r = 0; r < 4; ++r) {
          float v = sacc[mi][ni][r] * 0.125f;
          if constexpr (CROSS) {
            const int gq = qt * 32 + rq + r;
            v += sim[((size_t)(b * 12 + hh) * 1024 + gq) * 1024 + col]
               - smean[((size_t)b * 1024 + gq) * 1024 + col];
            if (!mask[((size_t)gq * 1024 + col) << msh]) v = -1e30f;
          }
          S[rq + r][col] = v;
        }
      }
    }
  }
  __syncthreads();

  { // phase 2: softmax rows [w*4, w*4+4), column-strided (bank-conflict-free)
    #pragma unroll
    for (int rr = 0; rr < 4; ++rr) {
      const int row = w * 4 + rr;
      float vv[16];
      #pragma unroll
      for (int j = 0; j < 16; ++j) vv[j] = S[row][lane + 64 * j];
      float m = vv[0];
      #pragma unroll
      for (int j = 1; j < 16; ++j) m = fmaxf(m, vv[j]);
      #pragma unroll
      for (int o = 32; o; o >>= 1) m = fmaxf(m, __shfl_xor(m, o));
      float s = 0.f;
      #pragma unroll
      for (int j = 0; j < 16; ++j) { vv[j] = __expf(vv[j] - m); s += vv[j]; }
      #pragma unroll
      for (int o = 32; o; o >>= 1) s += __shfl_xor(s, o);
      const float inv = 1.0f / s;
      bf16* prow = (bf16*)(&S[row][0]);
      #pragma unroll
      for (int j = 0; j < 16; ++j) prow[lane + 64 * j] = (bf16)(vv[j] * inv);
    }
  }
  __syncthreads();

  { // phase 3: wave w -> q-half (w>>2), d-tile (w&3)
    const int q2 = (w >> 2) * 16, dt = (w & 3) * 16;
    f32x4 oacc = {0.f, 0.f, 0.f, 0.f};
    const bf16* vb = Vt + ((size_t)(b * 12 + hh) * 64 + dt + l15) * 1024 + lg * 8;
    const bf16* pr = (const bf16*)(&S[q2 + l15][0]) + lg * 8;
    #pragma unroll 4
    for (int k0 = 0; k0 < 1024; k0 += 32) {
      const bf16x8 ap = *(const bf16x8*)(pr + k0);
      const bf16x8 bv = *(const bf16x8*)(vb + k0);
      oacc = mfma_bf16(ap, bv, oacc);
    }
    const int dcol = dt + l15;
    const int rq = q2 + lg * 4;
    #pragma unroll
    for (int r = 0; r < 4; ++r)
      Out[((size_t)(b * 1024 + qt * 32 + rq + r)) * 768 + hh * 64 + dcol] = (bf16)oacc[r];
  }
}

// ---------------- launcher ----------------
extern "C" void kernel_launch(void* const* d_in, const int* in_sizes, int n_in,
                              void* d_out, int out_size, void* d_ws, size_t ws_size,
                              hipStream_t stream)
{
  (void)in_sizes; (void)n_in; (void)out_size; (void)ws_size;
  const float* x    = (const float*)d_in[0];
  const float* y    = (const float*)d_in[1];
  const unsigned char* mask = (const unsigned char*)d_in[4];
  const float* sim  = (const float*)d_in[5];
  const float* ln1g = (const float*)d_in[6];
  const float* ln1b = (const float*)d_in[7];
  const float* ln2g = (const float*)d_in[8];
  const float* ln2b = (const float*)d_in[9];
  const float* ln3g = (const float*)d_in[10];
  const float* ln3b = (const float*)d_in[11];
  const float* lnyg = (const float*)d_in[12];
  const float* lnyb = (const float*)d_in[13];
  const float* qkvw = (const float*)d_in[14];
  const float* apw  = (const float*)d_in[15];
  const float* apb  = (const float*)d_in[16];
  const float* pqw  = (const float*)d_in[17];
  const float* pkw  = (const float*)d_in[18];
  const float* pvw  = (const float*)d_in[19];
  const float* cpw  = (const float*)d_in[20];
  const float* cpb  = (const float*)d_in[21];
  const float* f1w  = (const float*)d_in[22];
  const float* f1b  = (const float*)d_in[23];
  const float* f2w  = (const float*)d_in[24];
  const float* f2b  = (const float*)d_in[25];

  char* ws = (char*)d_ws;
  size_t off = 0;
  auto alloc = [&](size_t bytes) -> void* {
    off = (off + 255) & ~(size_t)255;
    void* p = ws + off;
    off += bytes;
    return p;
  };
  const size_t T = 4096;  // B*NQ
  bf16* w_qkv = (bf16*)alloc((size_t)2304 * 768 * 2);
  bf16* w_ap  = (bf16*)alloc((size_t)768 * 768 * 2);
  bf16* w_pq  = (bf16*)alloc((size_t)768 * 768 * 2);
  bf16* w_pk  = (bf16*)alloc((size_t)768 * 768 * 2);
  bf16* w_pv  = (bf16*)alloc((size_t)768 * 768 * 2);
  bf16* w_cp  = (bf16*)alloc((size_t)768 * 768 * 2);
  bf16* w_f1  = (bf16*)alloc((size_t)3072 * 768 * 2);
  bf16* w_f2  = (bf16*)alloc((size_t)768 * 3072 * 2);
  bf16* xn    = (bf16*)alloc(T * 768 * 2);
  bf16* qkvo  = (bf16*)alloc(T * 2304 * 2);
  bf16* vt    = (bf16*)alloc((size_t)48 * 64 * 1024 * 2);
  bf16* sa    = (bf16*)alloc(T * 768 * 2);
  float* x1   = (float*)alloc(T * 768 * 4);
  bf16* yln   = (bf16*)alloc(T * 768 * 2);
  bf16* xn2   = (bf16*)alloc(T * 768 * 2);
  bf16* cqf   = (bf16*)alloc(T * 768 * 2);
  bf16* ckf   = (bf16*)alloc(T * 768 * 2);
  bf16* cvf   = (bf16*)alloc(T * 768 * 2);
  bf16* cvtT  = (bf16*)alloc((size_t)48 * 64 * 1024 * 2);
  float* smean= (float*)alloc((size_t)4 * 1024 * 1024 * 4);
  bf16* ca    = (bf16*)alloc(T * 768 * 2);
  float* x2   = (float*)alloc(T * 768 * 4);
  bf16* xn3   = (bf16*)alloc(T * 768 * 2);
  bf16* hbuf  = (bf16*)alloc(T * 3072 * 2);
  int* mshift = (int*)alloc(256);

  detect_mask_k<<<1, 256, 0, stream>>>(mask, mshift);

  auto cvt = [&](const float* s, bf16* d, int n) {
    const int n4 = n / 4;
    cvt_k<<<(n4 + 255) / 256, 256, 0, stream>>>(s, d, n4);
  };
  cvt(qkvw, w_qkv, 2304 * 768);
  cvt(apw,  w_ap,  768 * 768);
  cvt(pqw,  w_pq,  768 * 768);
  cvt(pkw,  w_pk,  768 * 768);
  cvt(pvw,  w_pv,  768 * 768);
  cvt(cpw,  w_cp,  768 * 768);
  cvt(f1w,  w_f1,  3072 * 768);
  cvt(f2w,  w_f2,  768 * 3072);

  // ---- self-attention ----
  ln_k<<<4096, 256, 0, stream>>>(x, ln1g, ln1b, xn);
  gemm_bt<false,false,false,true><<<dim3(18, 32), 256, 0, stream>>>(
      xn, w_qkv, nullptr, nullptr, qkvo, nullptr, 4096, 2304, 768);
  build_vt<<<dim3(48, 16), 256, 0, stream>>>(qkvo + 1536, 2304, vt);
  attn_k<0><<<dim3(12, 32, 4), 512, 0, stream>>>(
      qkvo, 2304, qkvo + 768, 2304, vt, nullptr, nullptr, nullptr, nullptr, sa);
  gemm_bt<true,false,true,false><<<dim3(6, 32), 256, 0, stream>>>(
      sa, w_ap, apb, x, nullptr, x1, 4096, 768, 768);

  // ---- cross-attention ----
  ln_k<<<4096, 256, 0, stream>>>(y, lnyg, lnyb, yln);
  ln_k<<<4096, 256, 0, stream>>>(x1, ln2g, ln2b, xn2);
  gemm_bt<false,false,false,true><<<dim3(6, 32), 256, 0, stream>>>(
      xn2, w_pq, nullptr, nullptr, cqf, nullptr, 4096, 768, 768);
  gemm_bt<false,false,false,true><<<dim3(6, 32), 256, 0, stream>>>(
      yln, w_pk, nullptr, nullptr, ckf, nullptr, 4096, 768, 768);
  gemm_bt<false,false,false,true><<<dim3(6, 32), 256, 0, stream>>>(
      yln, w_pv, nullptr, nullptr, cvf, nullptr, 4096, 768, 768);
  build_vt<<<dim3(48, 16), 256, 0, stream>>>(cvf, 768, cvtT);
  simmean_k<<<4096, 256, 0, stream>>>(sim, smean);
  attn_k<1><<<dim3(12, 32, 4), 512, 0, stream>>>(
      cqf, 768, ckf, 768, cvtT, sim, smean, mask, mshift, ca);
  gemm_bt<true,false,true,false><<<dim3(6, 32), 256, 0, stream>>>(
      ca, w_cp, cpb, x1, nullptr, x2, 4096, 768, 768);

  // ---- MLP ----
  ln_k<<<4096, 256, 0, stream>>>(x2, ln3g, ln3b, xn3);
  gemm_bt<true,true,false,true><<<dim3(24, 32), 256, 0, stream>>>(
      xn3, w_f1, f1b, nullptr, hbuf, nullptr, 4096, 3072, 768);
  gemm_bt<true,false,true,false><<<dim3(6, 32), 256, 0, stream>>>(
      hbuf, w_f2, f2b, x2, nullptr, (float*)d_out, 4096, 768, 3072);

  // ---- y passthrough ----
  copy4_k<<<3072, 256, 0, stream>>>(y, (float*)d_out + 3145728, 786432);
}